// Round 4
// baseline (234.614 us; speedup 1.0000x reference)
//
#include <hip/hip_runtime.h>

// Bistable stochastic-resonance RK4 scan.
// x, noise: (64, 64, 4096) fp32 -> out: (64, 64, 4096) fp32
// 4096 independent sequences, one lane each; serial over T=4096.
//
// R2: divergent VMEM loads stalled the wave (~470 cyc/4 steps).
// R3: hand-rolled global_load_lds + manual vmcnt raced (>63 in-flight ops).
// R4: coalesced reg-staged LDS transpose, ALL waits compiler-managed:
//   - per 64-step tile: 32 coalesced f32x4 loads -> regs (issued a full tile
//     ahead; ~3000 cyc of compute hides the ~900 cyc HBM miss; compiler
//     inserts the counted vmcnt right before the ds_writes that consume them)
//   - ds_write_b128 / ds_read_b128 via slot-XOR swizzle (conflict-free)
//   - single wave per block: DS ops are same-wave in-order, no barriers
//   - output: divergent f32x4 stores, fire-and-forget (write-combines to
//     full 64B lines; R2 measured exact WRITE_SIZE with this pattern)

#define T_STEPS 4096
#define TILE    64
#define NTILES  (T_STEPS / TILE)   // 64
#define N_SEQ   4096

typedef float f32x4 __attribute__((ext_vector_type(4)));

__device__ __forceinline__ float rk4_step(float s, float i, float n) {
    const float H  = 0.01f;          // dt
    const float H2 = 0.005f;         // dt/2
    const float H6 = 0.01f / 6.0f;   // dt/6
    const float SD = 0.1f;           // sqrt(dt)

    float c1    = fmaf(H2, i, s);              // s + h2*i
    float c3    = fmaf(H,  i, s);              // s + h*i
    float basei = fmaf(H6, i, fmaf(SD, n, s)); // s + sd*n + h6*i

    float u1 = s * s;
    float p1 = H2 * s;
    float w1 = 1.0f - u1;
    float k1 = fmaf(s, w1, i);
    float y2 = fmaf(p1, w1, c1);

    float u2 = y2 * y2;
    float p2 = H2 * y2;
    float w2 = 1.0f - u2;
    float k2 = fmaf(y2, w2, i);
    float y3 = fmaf(p2, w2, c1);

    float u3 = y3 * y3;
    float p3 = H * y3;
    float w3 = 1.0f - u3;
    float k3 = fmaf(y3, w3, i);
    float y4 = fmaf(p3, w3, c3);

    float t12   = fmaf(2.0f, k2, k1);
    float tsum  = fmaf(2.0f, k3, t12);
    float base2 = fmaf(H6, tsum, basei);

    float u4 = y4 * y4;
    float z4 = H6 * y4;
    float w4 = 1.0f - u4;
    return fmaf(z4, w4, base2);
}

__global__ __launch_bounds__(64, 1) void bistable_sr_kernel(
        const float* __restrict__ x,
        const float* __restrict__ noise,
        float* __restrict__ out) {
    // LDS tile: [64 rows][16 slots] of f32x4, slot-XOR swizzled. 2 x 16 KB.
    __shared__ f32x4 lx[TILE * 16];
    __shared__ f32x4 ln[TILE * 16];

    const int l  = threadIdx.x;
    const int rl = l >> 4;            // 0..3: row offset within 4-row group
    const int sl = l & 15;            // 0..15: slot (16B column)
    const int xorl = l & 7;           // read-side swizzle for own row
    const size_t sb = (size_t)blockIdx.x * 64;   // first sequence of block

    // ---- prologue: load tile 0 into registers (coalesced, 1KB/instr) ----
    f32x4 xr[16], nr[16];
#pragma unroll
    for (int m = 0; m < 16; ++m) {
        const size_t g = (sb + 4 * m + rl) * T_STEPS + sl * 4;
        xr[m] = *(const f32x4*)(x + g);
        nr[m] = *(const f32x4*)(noise + g);
    }

    float s = 0.0f;
    float* po = out + (sb + l) * T_STEPS;   // lane-private output row

    for (int tau = 0; tau < NTILES; ++tau) {
        // ---- ds_write tile tau (compiler waits the feeding loads here) ----
#pragma unroll
        for (int m = 0; m < 16; ++m) {
            const int row  = 4 * m + rl;
            const int slot = sl ^ (row & 7);   // spread 8 rows over 8 slots
            lx[row * 16 + slot] = xr[m];
            ln[row * 16 + slot] = nr[m];
        }

        // ---- issue tile tau+1 loads (land during this tile's compute) ----
        const int nt = (tau + 1 < NTILES) ? tau + 1 : tau;  // clamp: redundant
#pragma unroll
        for (int m = 0; m < 16; ++m) {
            const size_t g = (sb + 4 * m + rl) * T_STEPS
                           + (size_t)nt * TILE + sl * 4;
            xr[m] = *(const f32x4*)(x + g);
            nr[m] = *(const f32x4*)(noise + g);
        }

        // ---- compute 64 steps from LDS (own row, swizzled slots) ----
#pragma unroll
        for (int j = 0; j < 16; ++j) {
            const int idx = l * 16 + (j ^ xorl);
            f32x4 xv = lx[idx];
            f32x4 nv = ln[idx];
            f32x4 o;
            s = rk4_step(s, xv.x, nv.x); o.x = s;
            s = rk4_step(s, xv.y, nv.y); o.y = s;
            s = rk4_step(s, xv.z, nv.z); o.z = s;
            s = rk4_step(s, xv.w, nv.w); o.w = s;
            *(f32x4*)(po + tau * TILE + j * 4) = o;   // fire-and-forget
        }
    }
}

extern "C" void kernel_launch(void* const* d_in, const int* in_sizes, int n_in,
                              void* d_out, int out_size, void* d_ws, size_t ws_size,
                              hipStream_t stream) {
    const float* x     = (const float*)d_in[0];
    const float* noise = (const float*)d_in[1];
    float* out = (float*)d_out;

    dim3 grid(N_SEQ / 64);   // 64 blocks x 1 wave, spread across CUs
    dim3 block(64);
    bistable_sr_kernel<<<grid, block, 0, stream>>>(x, noise, out);
}

// Round 5
// 201.640 us; speedup vs baseline: 1.1635x; 1.1635x over previous
//
#include <hip/hip_runtime.h>

// Bistable stochastic-resonance RK4 scan.
// x, noise: (64, 64, 4096) fp32 -> out: (64, 64, 4096) fp32
// 4096 independent sequences, one lane each; serial over T=4096.
//
// Wall time = one compute wave's in-order instruction stream (R4 lesson:
// with 1 wave/CU nothing hides VMEM/LDS latency). R5: producer-consumer.
//   wave 0 (compute): per 4 steps just 2 ds_read_b128 + 104 VALU + 1
//     ds_write_b128. No VMEM at all.
//   wave 1 (memory): coalesced global loads -> regs (pipelined one tile
//     ahead) -> linear ds_writes; output flush via linear ds_read +
//     coalesced stores. All waits compiler-managed (no manual vmcnt).
// Swizzle lives on the GLOBAL address side (goff): LDS[row][slot] holds
// global col = slot ^ (row&7); every LDS access pattern is the b128
// hardware minimum (8 lanes per 4-bank group, uniform).
// Double-buffered 32-step tiles, 48 KB LDS, 1 barrier/tile at a uniform
// call site (both waves execute all 129 barriers).

#define T_STEPS 4096
#define N_SEQ   4096
#define TILE    32
#define NT      (T_STEPS / TILE)      // 128 tiles
#define ROW_BYTES (T_STEPS * 4)       // 16384 B per sequence stream
#define TB      (TILE * 4)            // 128 B per row per tile

typedef float f32x4 __attribute__((ext_vector_type(4)));

__device__ __forceinline__ float rk4_step(float s, float i, float n) {
    const float H  = 0.01f;          // dt
    const float H2 = 0.005f;         // dt/2
    const float H6 = 0.01f / 6.0f;   // dt/6
    const float SD = 0.1f;           // sqrt(dt)

    float c1    = fmaf(H2, i, s);              // s + h2*i
    float c3    = fmaf(H,  i, s);              // s + h*i
    float basei = fmaf(H6, i, fmaf(SD, n, s)); // s + sd*n + h6*i

    float u1 = s * s;
    float p1 = H2 * s;
    float w1 = 1.0f - u1;
    float k1 = fmaf(s, w1, i);
    float y2 = fmaf(p1, w1, c1);

    float u2 = y2 * y2;
    float p2 = H2 * y2;
    float w2 = 1.0f - u2;
    float k2 = fmaf(y2, w2, i);
    float y3 = fmaf(p2, w2, c1);

    float u3 = y3 * y3;
    float p3 = H * y3;
    float w3 = 1.0f - u3;
    float k3 = fmaf(y3, w3, i);
    float y4 = fmaf(p3, w3, c3);

    float t12   = fmaf(2.0f, k2, k1);
    float tsum  = fmaf(2.0f, k3, t12);
    float base2 = fmaf(H6, tsum, basei);

    float u4 = y4 * y4;
    float z4 = H6 * y4;
    float w4 = 1.0f - u4;
    return fmaf(z4, w4, base2);
}

__global__ __launch_bounds__(128, 1) void bistable_sr_kernel(
        const float* __restrict__ x,
        const float* __restrict__ noise,
        float* __restrict__ out) {
    // [2 bufs][8 k-groups * 64 lanes] of f32x4 = 8 KB per buf per array.
    __shared__ f32x4 ibx[2][512];
    __shared__ f32x4 ibn[2][512];
    __shared__ f32x4 obf[2][512];

    const int tid = threadIdx.x;
    const int wid = tid >> 6;        // 0 = compute, 1 = memory
    const int l   = tid & 63;
    const size_t sb = (size_t)blockIdx.x * 64;   // first sequence of block

    // ---- wave-1 state (pre-swizzled global byte offsets + reg pipeline) --
    const char* xb = (const char*)(x + sb * T_STEPS);
    const char* nb = (const char*)(noise + sb * T_STEPS);
    char*       ob = (char*)(out + sb * T_STEPS);

    int goff[8];
#pragma unroll
    for (int k = 0; k < 8; ++k) {
        const int r = 8 * k + (l >> 3);                    // row 0..63
        goff[k] = r * ROW_BYTES + (((l & 7) ^ (r & 7)) << 4);
    }

    f32x4 xr[8], nr[8];
    if (wid == 1) {
        // Load tile 0, commit to buf 0, then load tile 1 into regs.
#pragma unroll
        for (int k = 0; k < 8; ++k) {
            xr[k] = *(const f32x4*)(xb + goff[k]);
            nr[k] = *(const f32x4*)(nb + goff[k]);
        }
#pragma unroll
        for (int k = 0; k < 8; ++k) {
            ibx[0][k * 64 + l] = xr[k];      // linear ds_write (min-conflict)
            ibn[0][k * 64 + l] = nr[k];
        }
#pragma unroll
        for (int k = 0; k < 8; ++k) {
            xr[k] = *(const f32x4*)(xb + goff[k] + TB);
            nr[k] = *(const f32x4*)(nb + goff[k] + TB);
        }
    }

    const int xorl = l & 7;
    float s = 0.0f;

    __syncthreads();                 // tile 0 staged

    for (int tau = 0; tau < NT; ++tau) {
        const int b = tau & 1;
        if (wid == 0) {
            // ---------- compute 32 steps from buf b ----------
            const f32x4* px = &ibx[b][l * 8];
            const f32x4* pn = &ibn[b][l * 8];
            f32x4*       po = &obf[b][l * 8];

            f32x4 xv = px[0 ^ xorl], nv = pn[0 ^ xorl];
#pragma unroll
            for (int j = 0; j < 8; ++j) {
                f32x4 xv2, nv2;
                if (j < 7) {                 // static (unrolled): reg pipeline
                    xv2 = px[(j + 1) ^ xorl];
                    nv2 = pn[(j + 1) ^ xorl];
                }
                f32x4 o;
                s = rk4_step(s, xv.x, nv.x); o.x = s;
                s = rk4_step(s, xv.y, nv.y); o.y = s;
                s = rk4_step(s, xv.z, nv.z); o.z = s;
                s = rk4_step(s, xv.w, nv.w); o.w = s;
                po[j ^ xorl] = o;
                xv = xv2; nv = nv2;
            }
        } else {
            // ---------- memory wave ----------
            if (tau + 1 < NT) {
                // commit regs (tile tau+1) to buf b^1; compiler inserts the
                // vmcnt wait here — loads were issued a full tile ago.
#pragma unroll
                for (int k = 0; k < 8; ++k) {
                    ibx[b ^ 1][k * 64 + l] = xr[k];
                    ibn[b ^ 1][k * 64 + l] = nr[k];
                }
                if (tau + 2 < NT) {
#pragma unroll
                    for (int k = 0; k < 8; ++k) {
                        xr[k] = *(const f32x4*)(xb + goff[k] + (tau + 2) * TB);
                        nr[k] = *(const f32x4*)(nb + goff[k] + (tau + 2) * TB);
                    }
                }
            }
            if (tau >= 1) {
                // flush tile tau-1: linear ds_read + pre-swizzled store
#pragma unroll
                for (int k = 0; k < 8; ++k) {
                    f32x4 v = obf[(tau - 1) & 1][k * 64 + l];
                    *(f32x4*)(ob + goff[k] + (tau - 1) * TB) = v;
                }
            }
        }
        __syncthreads();             // uniform site: both waves, every tile
    }

    if (wid == 1) {                  // flush last tile
#pragma unroll
        for (int k = 0; k < 8; ++k) {
            f32x4 v = obf[(NT - 1) & 1][k * 64 + l];
            *(f32x4*)(ob + goff[k] + (NT - 1) * TB) = v;
        }
    }
}

extern "C" void kernel_launch(void* const* d_in, const int* in_sizes, int n_in,
                              void* d_out, int out_size, void* d_ws, size_t ws_size,
                              hipStream_t stream) {
    const float* x     = (const float*)d_in[0];
    const float* noise = (const float*)d_in[1];
    float* out = (float*)d_out;

    dim3 grid(N_SEQ / 64);   // 64 blocks; compute wave alone on its CU
    dim3 block(128);         // wave 0 compute + wave 1 memory
    bistable_sr_kernel<<<grid, block, 0, stream>>>(x, noise, out);
}